// Round 1
// baseline (25228.351 us; speedup 1.0000x reference)
//
#include <hip/hip_runtime.h>

#define B_ 16
#define T_ 256
#define E_ 512
#define H_ 1024
#define V_ 32000

// ---------------------------------------------------------------------------
// Embedding gather: x0[bt, e] = emb[tokens[bt], e]   (float4 copies)
// ---------------------------------------------------------------------------
__global__ __launch_bounds__(256)
void gather_k(const int* __restrict__ tokens, const float* __restrict__ emb,
              float* __restrict__ x0)
{
    int i  = blockIdx.x * 256 + threadIdx.x;   // float4 index; total 4096*128
    int bt = i >> 7;                           // 128 float4 per row (E=512)
    int e4 = i & 127;
    int tok = tokens[bt];
    ((float4*)x0)[i] = ((const float4*)(emb + (size_t)tok * E_))[e4];
}

// ---------------------------------------------------------------------------
// fp32 SGEMM: C[M,N] = A[M,K] @ B[K,N] + bias[N]
// 128x128 tile, BK=8, 256 threads, 8x8 per thread.
// DO_MASK: rows with tokens[row]==0 get one-hot(0) instead (final logits).
// M,N multiples of 128; K multiple of 8 (holds for all three GEMMs here).
// ---------------------------------------------------------------------------
template<int DO_MASK>
__global__ __launch_bounds__(256)
void sgemm_k(const float* __restrict__ A, const float* __restrict__ Bm,
             const float* __restrict__ bias, float* __restrict__ C,
             const int* __restrict__ tokens, int M, int N, int K)
{
    __shared__ float As[8][128];   // A tile stored transposed [k][m]
    __shared__ float Bs[8][128];   // [k][n]

    const int tid = threadIdx.x;
    const int bm  = blockIdx.y * 128;
    const int bn  = blockIdx.x * 128;
    const int tx  = tid & 15;
    const int ty  = tid >> 4;

    // staging indices
    const int arow = tid >> 1;          // 0..127
    const int acol = (tid & 1) * 4;     // 0 or 4
    const int brow = tid >> 5;          // 0..7
    const int bcol = (tid & 31) * 4;    // 0..124

    const float* Ap = A  + (size_t)(bm + arow) * K + acol;
    const float* Bp = Bm + (size_t)brow * N + bn + bcol;

    float acc[8][8];
    #pragma unroll
    for (int i = 0; i < 8; ++i)
        #pragma unroll
        for (int j = 0; j < 8; ++j) acc[i][j] = 0.f;

    for (int kt = 0; kt < K; kt += 8) {
        float4 av = *(const float4*)(Ap + kt);
        float4 bv = *(const float4*)(Bp + (size_t)kt * N);
        __syncthreads();               // previous compute done reading LDS
        As[acol + 0][arow] = av.x;
        As[acol + 1][arow] = av.y;
        As[acol + 2][arow] = av.z;
        As[acol + 3][arow] = av.w;
        *(float4*)&Bs[brow][bcol] = bv;
        __syncthreads();
        #pragma unroll
        for (int k = 0; k < 8; ++k) {
            float4 a0 = *(const float4*)&As[k][ty * 4];
            float4 a1 = *(const float4*)&As[k][ty * 4 + 64];
            float4 b0 = *(const float4*)&Bs[k][tx * 4];
            float4 b1 = *(const float4*)&Bs[k][tx * 4 + 64];
            float a[8] = {a0.x, a0.y, a0.z, a0.w, a1.x, a1.y, a1.z, a1.w};
            float b[8] = {b0.x, b0.y, b0.z, b0.w, b1.x, b1.y, b1.z, b1.w};
            #pragma unroll
            for (int i = 0; i < 8; ++i)
                #pragma unroll
                for (int j = 0; j < 8; ++j)
                    acc[i][j] += a[i] * b[j];
        }
    }

    #pragma unroll
    for (int i = 0; i < 8; ++i) {
        int row = bm + (i >> 2) * 64 + ty * 4 + (i & 3);
        bool msk = true;
        if (DO_MASK) msk = (tokens[row] != 0);
        #pragma unroll
        for (int jh = 0; jh < 2; ++jh) {
            int col = bn + jh * 64 + tx * 4;
            float4 v;
            v.x = acc[i][jh * 4 + 0] + bias[col + 0];
            v.y = acc[i][jh * 4 + 1] + bias[col + 1];
            v.z = acc[i][jh * 4 + 2] + bias[col + 2];
            v.w = acc[i][jh * 4 + 3] + bias[col + 3];
            if (DO_MASK && !msk) {
                v.x = (col == 0) ? 1.f : 0.f;  // one-hot row for masked steps
                v.y = 0.f; v.z = 0.f; v.w = 0.f;
            }
            *(float4*)&C[(size_t)row * N + col] = v;
        }
    }
}

// ---------------------------------------------------------------------------
// One LSTM timestep: z = xz[:,t,:] + h_prev @ Wh; gates; h,c update w/ mask.
// grid 512 blocks x 128 threads; block handles 2 hidden units u for all
// 16 batches x 4 gates. h_prev staged TRANSPOSED in LDS (hs[k][b]) so the
// inner loop reads 16 distinct banks (conflict-free). Gate combine via
// __shfl within the 64-lane wave (lanes b, b+16, b+32, b+48 = gates i,f,g,o).
// ---------------------------------------------------------------------------
__global__ __launch_bounds__(128)
void lstm_step_k(const float* __restrict__ xz,   // [B*T, 4H] rows bt=b*T+t
                 const float* __restrict__ Wh,   // [H, 4H]
                 float* __restrict__ hseq,       // [B*T, H]
                 float* __restrict__ cst,        // [B*H]
                 const int* __restrict__ tokens, // [B*T]
                 int t)
{
    __shared__ float hs[H_][16];                 // 64 KB: hs[k][b] = h_prev[b][k]
    const int tid = threadIdx.x;

    for (int i = tid * 4; i < 16 * H_; i += 128 * 4) {
        int b = i >> 10;
        int k = i & (H_ - 1);
        float4 v = make_float4(0.f, 0.f, 0.f, 0.f);
        if (t > 0)
            v = *(const float4*)&hseq[((size_t)(b * T_ + t - 1)) * H_ + k];
        hs[k + 0][b] = v.x;
        hs[k + 1][b] = v.y;
        hs[k + 2][b] = v.z;
        hs[k + 3][b] = v.w;
    }
    __syncthreads();

    const int lane = tid & 63;
    const int b    = lane & 15;
    const int g    = lane >> 4;                  // 0=i 1=f 2=g 3=o
    const int uu   = tid >> 6;                   // wave id: 0 or 1
    const int u    = blockIdx.x * 2 + uu;
    const int j    = g * H_ + u;

    const float* wp = Wh + j;
    float a0 = 0.f, a1 = 0.f, a2 = 0.f, a3 = 0.f;
    #pragma unroll 8
    for (int k = 0; k < H_; k += 4) {
        a0 += hs[k + 0][b] * wp[(size_t)(k + 0) * (4 * H_)];
        a1 += hs[k + 1][b] * wp[(size_t)(k + 1) * (4 * H_)];
        a2 += hs[k + 2][b] * wp[(size_t)(k + 2) * (4 * H_)];
        a3 += hs[k + 3][b] * wp[(size_t)(k + 3) * (4 * H_)];
    }
    float z = xz[((size_t)(b * T_ + t)) * (4 * H_) + j] + ((a0 + a1) + (a2 + a3));

    // gather the four gate pre-activations onto the g==0 lanes
    float zf = __shfl(z, b + 16, 64);
    float zg = __shfl(z, b + 32, 64);
    float zo = __shfl(z, b + 48, 64);

    if (g == 0) {
        float i_ = 1.f / (1.f + expf(-z));
        float f_ = 1.f / (1.f + expf(-zf));
        float g_ = tanhf(zg);
        float o_ = 1.f / (1.f + expf(-zo));
        float c_old = (t > 0) ? cst[b * H_ + u] : 0.f;
        float c_new = f_ * c_old + i_ * g_;
        float h_new = o_ * tanhf(c_new);
        bool  m  = (tokens[b * T_ + t] != 0);
        float hp = hs[u][b];                     // h_prev[b][u]
        float h2 = m ? h_new : hp;
        float c2 = m ? c_new : c_old;
        cst[b * H_ + u] = c2;
        hseq[((size_t)(b * T_ + t)) * H_ + u] = h2;
    }
}

// ---------------------------------------------------------------------------
extern "C" void kernel_launch(void* const* d_in, const int* in_sizes, int n_in,
                              void* d_out, int out_size, void* d_ws, size_t ws_size,
                              hipStream_t stream)
{
    const int*   tokens = (const int*)d_in[0];
    const float* emb    = (const float*)d_in[1];
    const float* Wx0    = (const float*)d_in[2];
    const float* Wh0    = (const float*)d_in[3];
    const float* b0     = (const float*)d_in[4];
    const float* Wx1    = (const float*)d_in[5];
    const float* Wh1    = (const float*)d_in[6];
    const float* b1     = (const float*)d_in[7];
    const float* Wout   = (const float*)d_in[8];
    const float* bout   = (const float*)d_in[9];
    float* out = (float*)d_out;

    // workspace layout (floats): ~109 MB total
    float* ws = (float*)d_ws;
    float* x0 = ws;                              // 4096*512
    float* xz = x0 + (size_t)4096 * 512;         // 4096*4096 (reused L0/L1)
    float* h0 = xz + (size_t)4096 * 4096;        // 4096*1024
    float* h1 = h0 + (size_t)4096 * 1024;        // 4096*1024
    float* cs = h1 + (size_t)4096 * 1024;        // 16*1024

    gather_k<<<2048, 256, 0, stream>>>(tokens, emb, x0);

    dim3 blk(256);
    dim3 g12(4096 / 128, 4096 / 128);
    sgemm_k<0><<<g12, blk, 0, stream>>>(x0, Wx0, b0, xz, nullptr, 4096, 4096, 512);
    for (int t = 0; t < 256; ++t)
        lstm_step_k<<<512, 128, 0, stream>>>(xz, Wh0, h0, cs, tokens, t);

    sgemm_k<0><<<g12, blk, 0, stream>>>(h0, Wx1, b1, xz, nullptr, 4096, 4096, 1024);
    for (int t = 0; t < 256; ++t)
        lstm_step_k<<<512, 128, 0, stream>>>(xz, Wh1, h1, cs, tokens, t);

    dim3 g3(32000 / 128, 4096 / 128);
    sgemm_k<1><<<g3, blk, 0, stream>>>(h1, Wout, bout, out, tokens, 4096, 32000, 1024);
}